// Round 4
// baseline (65.617 us; speedup 1.0000x reference)
//
#include <hip/hip_runtime.h>

#define N_IN_   1024
#define N_OUT_  1536
#define N_CH    16
#define ROW0    340     // first input row/col index ever touched
#define N_ROWS  346     // rows 340..685 inclusive (actual use ≤684)
#define TY      6       // output rows per thread in pass 2 (6 | 768: no wrap straddle)
#define CPB     4       // channels per block in pass 2

// Catmull-Rom-style cubic kernel, matching the reference formula in f32.
__device__ __forceinline__ float cubic_w(float x) {
    float ax = fabsf(x);
    float f1 = 1.0f + ax * ax * (1.5f * ax - 2.5f);
    float t  = 2.0f - ax;
    float f2 = -0.5f * (ax - 1.0f) * t * t;
    return ax <= 1.0f ? f1 : (ax < 2.0f ? f2 : 0.0f);
}

__device__ __forceinline__ float u_of_j(int j) {
    const float c0 = -0.5f / 0.05f;                        // k_in[0] = -10
    const float c1 = (-0.5f + 1.0f / 1023.0f) / 0.05f;     // k_in[1]
    const float h  = c1 - c0;
    float kout = (-0.5f + (float)j * (1.0f / 1535.0f)) / 0.15f;
    return (kout - c0) / h;                                // in [341, 682]
}

// j = output index in pre-ifftshift space -> base tap index (i0-1) and weights.
__device__ __forceinline__ void axis_wts(int j, float* w, int& base) {
    float u = u_of_j(j);
    int i0 = (int)floorf(u);
    base = i0 - 1;
    #pragma unroll
    for (int d = 0; d < 4; ++d)
        w[d] = cubic_w(u - (float)(base + d));
}

// ---------------- Pass 1: resample along x ----------------
__global__ __launch_bounds__(256)
void pass1_x(const float* __restrict__ re, float* __restrict__ inter) {
    const int x  = blockIdx.x * 256 + threadIdx.x;  // final output col
    const int ir = blockIdx.y;                      // 0..N_ROWS-1
    const int jx = x < 768 ? x + 768 : x - 768;     // pre-ifftshift col

    float wx[4]; int bx;
    axis_wts(jx, wx, bx);
    bx = min(max(bx, 0), N_IN_ - 4);
    #pragma unroll
    for (int d = 0; d < 4; ++d) wx[d] *= 3.0f;      // fold RES_RATIO

    const int r    = ir + ROW0;
    const int rmem = (r >= 512) ? (r - 512) : (r + 512);   // fftshift row
    const size_t rbase = (size_t)rmem * N_IN_;

    // fftshift cols: contiguous unless window straddles idx 511->512
    const bool hi = (bx >= 512);
    const bool lo = (bx + 3 < 512);
    const bool contig = hi || lo;
    const int xoff = hi ? (bx - 512) : (bx + 512);
    int cm[4];
    #pragma unroll
    for (int d = 0; d < 4; ++d) {
        int t = bx + d;
        cm[d] = (t >= 512) ? (t - 512) : (t + 512);
    }

    for (int c = 0; c < N_CH; ++c) {
        const float* rrow = re + (size_t)c * (N_IN_ * N_IN_) + rbase;
        float v[4];
        if (contig) {
            __builtin_memcpy(v, rrow + xoff, 16);
        } else {
            #pragma unroll
            for (int d = 0; d < 4; ++d) v[d] = rrow[cm[d]];
        }
        float a = 0.0f;
        #pragma unroll
        for (int d = 0; d < 4; ++d) a = fmaf(wx[d], v[d], a);
        inter[((size_t)c * N_ROWS + ir) * N_OUT_ + x] = a;
    }
}

// ---------------- Pass 2: resample along y, tiled ----------------
// blockDim 128: lanes cover 512 x (float4 each). Each thread: TY y-rows x CPB ch.
__global__ __launch_bounds__(128)
void pass2_y(const float* __restrict__ inter, float* __restrict__ out) {
    const int x4 = blockIdx.x * 512 + threadIdx.x * 4;
    const int y0 = blockIdx.y * TY;
    const int c0 = blockIdx.z * CPB;
    const int jy0 = y0 < 768 ? y0 + 768 : y0 - 768;   // whole tile on one side

    // u for the TY outputs (contiguous jy)
    float u[TY];
    #pragma unroll
    for (int i = 0; i < TY; ++i) u[i] = u_of_j(jy0 + i);

    int base = (int)floorf(u[0]) - 1;                 // rows base..base+5 suffice
    int ir0 = base - ROW0;
    ir0 = min(max(ir0, 0), N_ROWS - 6);

    // 6x6 weight matrix vs the actually-loaded global rows; out-of-support
    // taps get exactly 0 from the cubic kernel.
    float wmat[TY][6];
    #pragma unroll
    for (int i = 0; i < TY; ++i)
        #pragma unroll
        for (int j = 0; j < 6; ++j)
            wmat[i][j] = cubic_w(u[i] - (float)(ROW0 + ir0 + j));

    #pragma unroll
    for (int cc = 0; cc < CPB; ++cc) {
        const int c = c0 + cc;
        const float* ib = inter + ((size_t)c * N_ROWS + ir0) * N_OUT_ + x4;
        float4 v[6];
        #pragma unroll
        for (int j = 0; j < 6; ++j)
            v[j] = *(const float4*)(ib + (size_t)j * N_OUT_);

        float* ob = out + (size_t)c * (N_OUT_ * N_OUT_) + (size_t)y0 * N_OUT_ + x4;
        #pragma unroll
        for (int i = 0; i < TY; ++i) {
            float4 a = make_float4(0.f, 0.f, 0.f, 0.f);
            #pragma unroll
            for (int j = 0; j < 6; ++j) {
                float w = wmat[i][j];
                a.x = fmaf(w, v[j].x, a.x);
                a.y = fmaf(w, v[j].y, a.y);
                a.z = fmaf(w, v[j].z, a.z);
                a.w = fmaf(w, v[j].w, a.w);
            }
            *(float4*)(ob + (size_t)i * N_OUT_) = a;
        }
    }
}

// ---------------- Fallback: fused single-pass (proven R2 kernel) -------------
template <bool CPLX>
__global__ __launch_bounds__(256)
void resample_kernel(const float* __restrict__ re,
                     const float* __restrict__ im,
                     float* __restrict__ out) {
    const int x = blockIdx.x * 256 + threadIdx.x;
    const int y = blockIdx.y;
    const int jx = x < 768 ? x + 768 : x - 768;
    const int jy = y < 768 ? y + 768 : y - 768;

    float wx[4], wy[4];
    int bx, by;
    axis_wts(jx, wx, bx);
    axis_wts(jy, wy, by);
    bx = min(max(bx, 0), N_IN_ - 4);
    by = min(max(by, 0), N_IN_ - 4);

    #pragma unroll
    for (int d = 0; d < 4; ++d) wy[d] *= 3.0f;

    float w[4][4];
    #pragma unroll
    for (int dy = 0; dy < 4; ++dy)
        #pragma unroll
        for (int dx = 0; dx < 4; ++dx) w[dy][dx] = wy[dy] * wx[dx];

    int rofs[4];
    #pragma unroll
    for (int dy = 0; dy < 4; ++dy) {
        int t = by + dy;
        int r = (t >= 512) ? (t - 512) : (t + 512);
        rofs[dy] = r * N_IN_;
    }

    const bool hi = (bx >= 512);
    const bool lo = (bx + 3 < 512);
    const bool contig = hi || lo;
    const int xoff = hi ? (bx - 512) : (bx + 512);
    int cm[4];
    #pragma unroll
    for (int d = 0; d < 4; ++d) {
        int t = bx + d;
        cm[d] = (t >= 512) ? (t - 512) : (t + 512);
    }

    const int outbase = y * N_OUT_ + x;

    for (int c = 0; c < N_CH; ++c) {
        const float* rec = re + (size_t)c * (N_IN_ * N_IN_);
        float ar = 0.0f, ai = 0.0f;
        #pragma unroll
        for (int dy = 0; dy < 4; ++dy) {
            const float* rrow = rec + rofs[dy];
            float vr[4];
            if (contig) {
                __builtin_memcpy(vr, rrow + xoff, 16);
            } else {
                #pragma unroll
                for (int d = 0; d < 4; ++d) vr[d] = rrow[cm[d]];
            }
            #pragma unroll
            for (int d = 0; d < 4; ++d) ar = fmaf(w[dy][d], vr[d], ar);

            if (CPLX) {
                const float* irow = im + (size_t)c * (N_IN_ * N_IN_) + rofs[dy];
                float vi[4];
                if (contig) {
                    __builtin_memcpy(vi, irow + xoff, 16);
                } else {
                    #pragma unroll
                    for (int d = 0; d < 4; ++d) vi[d] = irow[cm[d]];
                }
                #pragma unroll
                for (int d = 0; d < 4; ++d) ai = fmaf(w[dy][d], vi[d], ai);
            }
        }
        if (CPLX) {
            float2* o2 = (float2*)out;
            o2[(size_t)c * (N_OUT_ * N_OUT_) + outbase] = make_float2(ar, ai);
        } else {
            out[(size_t)c * (N_OUT_ * N_OUT_) + outbase] = ar;
        }
    }
}

extern "C" void kernel_launch(void* const* d_in, const int* in_sizes, int n_in,
                              void* d_out, int out_size, void* d_ws, size_t ws_size,
                              hipStream_t stream) {
    const float* re = (const float*)d_in[0];   // kimage_real (16,1024,1024)
    const float* im = (const float*)d_in[1];   // kimage_imag (16,1024,1024)
    float* out = (float*)d_out;

    const size_t inter_bytes = (size_t)N_CH * N_ROWS * N_OUT_ * sizeof(float);

    if (out_size >= 2 * N_CH * N_OUT_ * N_OUT_) {
        // complex-interleaved output (defensive; not the observed case)
        dim3 grid(N_OUT_ / 256, N_OUT_);
        resample_kernel<true><<<grid, dim3(256), 0, stream>>>(re, im, out);
    } else if (ws_size >= inter_bytes) {
        float* inter = (float*)d_ws;
        pass1_x<<<dim3(N_OUT_ / 256, N_ROWS), dim3(256), 0, stream>>>(re, inter);
        pass2_y<<<dim3(N_OUT_ / 512, N_OUT_ / TY, N_CH / CPB), dim3(128), 0, stream>>>(inter, out);
    } else {
        dim3 grid(N_OUT_ / 256, N_OUT_);
        resample_kernel<false><<<grid, dim3(256), 0, stream>>>(re, im, out);
    }
}

// Round 5
// 55.456 us; speedup vs baseline: 1.1832x; 1.1832x over previous
//
#include <hip/hip_runtime.h>

#define N_IN_   1024
#define N_OUT_  1536
#define N_CH    16
#define TY      6       // output rows per thread (6 | 768: tile never straddles ifftshift wrap)

// Catmull-Rom-style cubic kernel, matching the reference formula in f32.
__device__ __forceinline__ float cubic_w(float x) {
    float ax = fabsf(x);
    float f1 = 1.0f + ax * ax * (1.5f * ax - 2.5f);
    float t  = 2.0f - ax;
    float f2 = -0.5f * (ax - 1.0f) * t * t;
    return ax <= 1.0f ? f1 : (ax < 2.0f ? f2 : 0.0f);
}

__device__ __forceinline__ float u_of_j(int j) {
    const float c0 = -0.5f / 0.05f;                        // k_in[0] = -10
    const float c1 = (-0.5f + 1.0f / 1023.0f) / 0.05f;     // k_in[1]
    const float h  = c1 - c0;
    float kout = (-0.5f + (float)j * (1.0f / 1535.0f)) / 0.15f;
    return (kout - c0) / h;                                // in [341, 682]
}

// Fused separable resample: one thread = one output column x, TY output rows,
// all channels. x-resample held in registers; no intermediate buffer.
__global__ __launch_bounds__(256)
void fused_sep(const float* __restrict__ re, float* __restrict__ out) {
    const int x   = blockIdx.x * 256 + threadIdx.x;   // output col
    const int y0  = blockIdx.y * TY;                  // first output row of tile
    const int jx  = x  < 768 ? x  + 768 : x  - 768;   // pre-ifftshift col
    const int jy0 = y0 < 768 ? y0 + 768 : y0 - 768;   // pre-ifftshift row (tile contiguous)

    // ---- x weights + 4-tap window (per-thread), RES_RATIO=3 folded in ----
    float ux = u_of_j(jx);
    int bx = (int)floorf(ux) - 1;
    bx = min(max(bx, 0), N_IN_ - 4);
    float wx[4];
    #pragma unroll
    for (int d = 0; d < 4; ++d) wx[d] = 3.0f * cubic_w(ux - (float)(bx + d));

    // fftshift cols: contiguous unless window straddles idx 511->512
    const bool hi = (bx >= 512);
    const bool lo = (bx + 3 < 512);
    const bool contig = hi || lo;
    const int xoff = hi ? (bx - 512) : (bx + 512);
    int cm[4];
    #pragma unroll
    for (int d = 0; d < 4; ++d) {
        int t = bx + d;
        cm[d] = (t >= 512) ? (t - 512) : (t + 512);
    }

    // ---- y: 6-row input window base..base+5 covers all TY outputs' taps ----
    float uy0 = u_of_j(jy0);
    int byb = (int)floorf(uy0) - 1;                   // in [340, 680]
    byb = min(max(byb, 0), N_IN_ - 6);
    float wmat[TY][6];                                // out-of-support taps -> exact 0
    #pragma unroll
    for (int i = 0; i < TY; ++i) {
        float ui = u_of_j(jy0 + i);
        #pragma unroll
        for (int j = 0; j < 6; ++j)
            wmat[i][j] = cubic_w(ui - (float)(byb + j));
    }
    size_t rofs[6];                                   // fftshift rows
    #pragma unroll
    for (int j = 0; j < 6; ++j) {
        int r = byb + j;
        int rm = (r >= 512) ? (r - 512) : (r + 512);
        rofs[j] = (size_t)rm * N_IN_;
    }

    for (int c = 0; c < N_CH; ++c) {
        const float* rec = re + (size_t)c * (N_IN_ * N_IN_);
        // 6 gathers -> 6 x-resampled values in registers
        float xr[6];
        #pragma unroll
        for (int j = 0; j < 6; ++j) {
            const float* rrow = rec + rofs[j];
            float v[4];
            if (contig) {
                __builtin_memcpy(v, rrow + xoff, 16);
            } else {
                v[0] = rrow[cm[0]]; v[1] = rrow[cm[1]];
                v[2] = rrow[cm[2]]; v[3] = rrow[cm[3]];
            }
            float a = 0.0f;
            #pragma unroll
            for (int d = 0; d < 4; ++d) a = fmaf(wx[d], v[d], a);
            xr[j] = a;
        }
        // 6x6 y-combine -> TY outputs, coalesced dword stores
        float* ob = out + (size_t)c * (N_OUT_ * N_OUT_) + (size_t)y0 * N_OUT_ + x;
        #pragma unroll
        for (int i = 0; i < TY; ++i) {
            float a = 0.0f;
            #pragma unroll
            for (int j = 0; j < 6; ++j) a = fmaf(wmat[i][j], xr[j], a);
            ob[(size_t)i * N_OUT_] = a;
        }
    }
}

// ---------------- Defensive: complex-interleaved output variant --------------
__global__ __launch_bounds__(256)
void resample_cplx(const float* __restrict__ re,
                   const float* __restrict__ im,
                   float2* __restrict__ out) {
    const int x = blockIdx.x * 256 + threadIdx.x;
    const int y = blockIdx.y;
    const int jx = x < 768 ? x + 768 : x - 768;
    const int jy = y < 768 ? y + 768 : y - 768;

    float ux = u_of_j(jx), uy = u_of_j(jy);
    int bx = min(max((int)floorf(ux) - 1, 0), N_IN_ - 4);
    int by = min(max((int)floorf(uy) - 1, 0), N_IN_ - 4);
    float wx[4], wy[4];
    #pragma unroll
    for (int d = 0; d < 4; ++d) {
        wx[d] = cubic_w(ux - (float)(bx + d));
        wy[d] = 3.0f * cubic_w(uy - (float)(by + d));
    }
    float w[4][4];
    #pragma unroll
    for (int dy = 0; dy < 4; ++dy)
        #pragma unroll
        for (int dx = 0; dx < 4; ++dx) w[dy][dx] = wy[dy] * wx[dx];

    int rofs[4];
    #pragma unroll
    for (int dy = 0; dy < 4; ++dy) {
        int t = by + dy;
        rofs[dy] = ((t >= 512) ? (t - 512) : (t + 512)) * N_IN_;
    }
    int cm[4];
    #pragma unroll
    for (int d = 0; d < 4; ++d) {
        int t = bx + d;
        cm[d] = (t >= 512) ? (t - 512) : (t + 512);
    }

    const int outbase = y * N_OUT_ + x;
    for (int c = 0; c < N_CH; ++c) {
        const float* rec = re + (size_t)c * (N_IN_ * N_IN_);
        const float* imc = im + (size_t)c * (N_IN_ * N_IN_);
        float ar = 0.0f, ai = 0.0f;
        #pragma unroll
        for (int dy = 0; dy < 4; ++dy) {
            #pragma unroll
            for (int d = 0; d < 4; ++d) {
                ar = fmaf(w[dy][d], rec[rofs[dy] + cm[d]], ar);
                ai = fmaf(w[dy][d], imc[rofs[dy] + cm[d]], ai);
            }
        }
        out[(size_t)c * (N_OUT_ * N_OUT_) + outbase] = make_float2(ar, ai);
    }
}

extern "C" void kernel_launch(void* const* d_in, const int* in_sizes, int n_in,
                              void* d_out, int out_size, void* d_ws, size_t ws_size,
                              hipStream_t stream) {
    const float* re = (const float*)d_in[0];   // kimage_real (16,1024,1024)
    const float* im = (const float*)d_in[1];   // kimage_imag (16,1024,1024)

    if (out_size >= 2 * N_CH * N_OUT_ * N_OUT_) {
        // complex-interleaved output (defensive; not the observed case)
        resample_cplx<<<dim3(N_OUT_ / 256, N_OUT_), dim3(256), 0, stream>>>(
            re, im, (float2*)d_out);
    } else {
        fused_sep<<<dim3(N_OUT_ / 256, N_OUT_ / TY), dim3(256), 0, stream>>>(
            re, (float*)d_out);
    }
}

// Round 6
// 43.355 us; speedup vs baseline: 1.5135x; 1.2791x over previous
//
#include <hip/hip_runtime.h>

#define N_IN_   1024
#define N_OUT_  1536
#define N_CH    16
#define TY      6       // output rows per block tile (6 | 768: never straddles ifftshift wrap)
#define XT      256     // output cols per block tile (256 | 768)
#define XW      64      // staged input x-window (max span 57+5 < 64)

// Catmull-Rom-style cubic kernel, matching the reference formula in f32.
// Exact 0 for |x| >= 2 -> widened tap windows are formula-identical.
__device__ __forceinline__ float cubic_w(float x) {
    float ax = fabsf(x);
    float f1 = 1.0f + ax * ax * (1.5f * ax - 2.5f);
    float t  = 2.0f - ax;
    float f2 = -0.5f * (ax - 1.0f) * t * t;
    return ax <= 1.0f ? f1 : (ax < 2.0f ? f2 : 0.0f);
}

__device__ __forceinline__ float u_of_j(int j) {
    const float c0 = -0.5f / 0.05f;                        // k_in[0] = -10
    const float c1 = (-0.5f + 1.0f / 1023.0f) / 0.05f;     // k_in[1]
    const float h  = c1 - c0;
    float kout = (-0.5f + (float)j * (1.0f / 1535.0f)) / 0.15f;
    return (kout - c0) / h;                                // in [341, 682]
}

// One block: output tile [y0..y0+5] x [X0..X0+255] x all 16 channels.
// Stage 16ch x 6rows x 64cols of input in LDS, then register-blocked
// separable resample with float4 stores.
__global__ __launch_bounds__(256)
void fused_lds(const float* __restrict__ re, float* __restrict__ out) {
    const int tid = threadIdx.x;
    const int X0  = blockIdx.x * XT;
    const int y0  = blockIdx.y * TY;
    const int jx0 = X0 < 768 ? X0 + 768 : X0 - 768;   // contiguous over tile
    const int jy0 = y0 < 768 ? y0 + 768 : y0 - 768;

    // x stage window: covers all taps of the 256 output cols
    int stage_b = (int)floorf(u_of_j(jx0)) - 1;
    stage_b = min(max(stage_b, 0), N_IN_ - XW);
    // y input window: 6 rows cover all taps of the 6 output rows
    int byb = (int)floorf(u_of_j(jy0)) - 1;
    byb = min(max(byb, 0), N_IN_ - TY);

    __shared__ float lds[N_CH][TY][XW];

    // ---- stage: 96 segments of 64 contiguous-ish floats, coalesced ----
    {
        const int e = tid & 63;
        const int t = stage_b + e;
        const int cmem = (t >= 512) ? (t - 512) : (t + 512);   // fftshift col
        for (int s = tid >> 6; s < N_CH * TY; s += 4) {
            const int ch  = s / TY;
            const int row = s - ch * TY;
            const int r   = byb + row;
            const int rm  = (r >= 512) ? (r - 512) : (r + 512); // fftshift row
            lds[ch][row][e] =
                re[(size_t)ch * (N_IN_ * N_IN_) + (size_t)rm * N_IN_ + cmem];
        }
    }

    // ---- weights (overlap with staging loads) ----
    // y 6x6 matrix, block-uniform; RES_RATIO=3 folded here.
    float wmat[TY][TY];
    #pragma unroll
    for (int i = 0; i < TY; ++i) {
        float ui = u_of_j(jy0 + i);
        #pragma unroll
        for (int j = 0; j < TY; ++j)
            wmat[i][j] = 3.0f * cubic_w(ui - (float)(byb + j));
    }

    // per-thread: 4 consecutive output cols, one 6-wide x window
    const int xq  = tid & 63;       // which col-quad
    const int cg  = tid >> 6;       // channel group (4 ch each)
    const int x0l = xq * 4;
    float wx6[4][6];
    int w0;
    {
        float u0 = u_of_j(jx0 + x0l);
        w0 = (int)floorf(u0) - 1 - stage_b;       // 0..57
        w0 = min(max(w0, 0), XW - 6);
        #pragma unroll
        for (int k = 0; k < 4; ++k) {
            float uk = u_of_j(jx0 + x0l + k);
            #pragma unroll
            for (int j = 0; j < 6; ++j)
                wx6[k][j] = cubic_w(uk - (float)(stage_b + w0 + j));
        }
    }

    __syncthreads();

    #pragma unroll
    for (int cc = 0; cc < 4; ++cc) {
        const int c = cg * 4 + cc;
        float acc[TY][4];
        #pragma unroll
        for (int i = 0; i < TY; ++i)
            #pragma unroll
            for (int k = 0; k < 4; ++k) acc[i][k] = 0.0f;

        #pragma unroll
        for (int j = 0; j < TY; ++j) {
            const float* p = &lds[c][j][w0];
            const float L0 = p[0], L1 = p[1], L2 = p[2],
                        L3 = p[3], L4 = p[4], L5 = p[5];
            float xr0, xr1, xr2, xr3;
            xr0 = fmaf(wx6[0][5], L5, fmaf(wx6[0][4], L4, fmaf(wx6[0][3], L3,
                  fmaf(wx6[0][2], L2, fmaf(wx6[0][1], L1, wx6[0][0] * L0)))));
            xr1 = fmaf(wx6[1][5], L5, fmaf(wx6[1][4], L4, fmaf(wx6[1][3], L3,
                  fmaf(wx6[1][2], L2, fmaf(wx6[1][1], L1, wx6[1][0] * L0)))));
            xr2 = fmaf(wx6[2][5], L5, fmaf(wx6[2][4], L4, fmaf(wx6[2][3], L3,
                  fmaf(wx6[2][2], L2, fmaf(wx6[2][1], L1, wx6[2][0] * L0)))));
            xr3 = fmaf(wx6[3][5], L5, fmaf(wx6[3][4], L4, fmaf(wx6[3][3], L3,
                  fmaf(wx6[3][2], L2, fmaf(wx6[3][1], L1, wx6[3][0] * L0)))));
            #pragma unroll
            for (int i = 0; i < TY; ++i) {
                const float w = wmat[i][j];
                acc[i][0] = fmaf(w, xr0, acc[i][0]);
                acc[i][1] = fmaf(w, xr1, acc[i][1]);
                acc[i][2] = fmaf(w, xr2, acc[i][2]);
                acc[i][3] = fmaf(w, xr3, acc[i][3]);
            }
        }

        float* ob = out + (size_t)c * (N_OUT_ * N_OUT_)
                        + (size_t)y0 * N_OUT_ + X0 + x0l;
        #pragma unroll
        for (int i = 0; i < TY; ++i) {
            float4 a = make_float4(acc[i][0], acc[i][1], acc[i][2], acc[i][3]);
            *(float4*)(ob + (size_t)i * N_OUT_) = a;
        }
    }
}

// ---------------- Defensive: complex-interleaved output variant --------------
__global__ __launch_bounds__(256)
void resample_cplx(const float* __restrict__ re,
                   const float* __restrict__ im,
                   float2* __restrict__ out) {
    const int x = blockIdx.x * 256 + threadIdx.x;
    const int y = blockIdx.y;
    const int jx = x < 768 ? x + 768 : x - 768;
    const int jy = y < 768 ? y + 768 : y - 768;

    float ux = u_of_j(jx), uy = u_of_j(jy);
    int bx = min(max((int)floorf(ux) - 1, 0), N_IN_ - 4);
    int by = min(max((int)floorf(uy) - 1, 0), N_IN_ - 4);
    float wx[4], wy[4];
    #pragma unroll
    for (int d = 0; d < 4; ++d) {
        wx[d] = cubic_w(ux - (float)(bx + d));
        wy[d] = 3.0f * cubic_w(uy - (float)(by + d));
    }
    float w[4][4];
    #pragma unroll
    for (int dy = 0; dy < 4; ++dy)
        #pragma unroll
        for (int dx = 0; dx < 4; ++dx) w[dy][dx] = wy[dy] * wx[dx];

    int rofs[4];
    #pragma unroll
    for (int dy = 0; dy < 4; ++dy) {
        int t = by + dy;
        rofs[dy] = ((t >= 512) ? (t - 512) : (t + 512)) * N_IN_;
    }
    int cm[4];
    #pragma unroll
    for (int d = 0; d < 4; ++d) {
        int t = bx + d;
        cm[d] = (t >= 512) ? (t - 512) : (t + 512);
    }

    const int outbase = y * N_OUT_ + x;
    for (int c = 0; c < N_CH; ++c) {
        const float* rec = re + (size_t)c * (N_IN_ * N_IN_);
        const float* imc = im + (size_t)c * (N_IN_ * N_IN_);
        float ar = 0.0f, ai = 0.0f;
        #pragma unroll
        for (int dy = 0; dy < 4; ++dy) {
            #pragma unroll
            for (int d = 0; d < 4; ++d) {
                ar = fmaf(w[dy][d], rec[rofs[dy] + cm[d]], ar);
                ai = fmaf(w[dy][d], imc[rofs[dy] + cm[d]], ai);
            }
        }
        out[(size_t)c * (N_OUT_ * N_OUT_) + outbase] = make_float2(ar, ai);
    }
}

extern "C" void kernel_launch(void* const* d_in, const int* in_sizes, int n_in,
                              void* d_out, int out_size, void* d_ws, size_t ws_size,
                              hipStream_t stream) {
    const float* re = (const float*)d_in[0];   // kimage_real (16,1024,1024)
    const float* im = (const float*)d_in[1];   // kimage_imag (16,1024,1024)

    if (out_size >= 2 * N_CH * N_OUT_ * N_OUT_) {
        // complex-interleaved output (defensive; not the observed case)
        resample_cplx<<<dim3(N_OUT_ / 256, N_OUT_), dim3(256), 0, stream>>>(
            re, im, (float2*)d_out);
    } else {
        fused_lds<<<dim3(N_OUT_ / XT, N_OUT_ / TY), dim3(256), 0, stream>>>(
            re, (float*)d_out);
    }
}